// Round 1
// baseline (205.850 us; speedup 1.0000x reference)
//
#include <hip/hip_runtime.h>
#include <hip/hip_bf16.h>

// Problem constants
#define BATCH 32
#define LSEQ  2048
#define DIN   64
#define NC    32
#define DC    16
// out: [32, 32, 16] fp32

// ---------------------------------------------------------------------------
// Kernel 1: v0[b][d] = sum_l u[b,l,d]   (iteration-0 c is uniform 1/32)
// grid 256 (b = bid>>3, 256-l chunk = bid&7), 256 threads
// ---------------------------------------------------------------------------
__global__ void k_sum_u(const float* __restrict__ u, float* __restrict__ v0) {
    int b  = blockIdx.x >> 3;
    int l0 = (blockIdx.x & 7) * 256;
    int q  = threadIdx.x & 15;   // float4 column (d = 4q..4q+3)
    int r  = threadIdx.x >> 4;   // 0..15 row offset
    const float4* u4 = (const float4*)u;
    float4 acc = {0.f, 0.f, 0.f, 0.f};
#pragma unroll
    for (int j = 0; j < 16; ++j) {
        int l = l0 + r + 16 * j;
        float4 x = u4[(b * LSEQ + l) * 16 + q];
        acc.x += x.x; acc.y += x.y; acc.z += x.z; acc.w += x.w;
    }
    __shared__ float red[16][64];
    red[r][q * 4 + 0] = acc.x;
    red[r][q * 4 + 1] = acc.y;
    red[r][q * 4 + 2] = acc.z;
    red[r][q * 4 + 3] = acc.w;
    __syncthreads();
    if (threadIdx.x < 64) {
        float s = 0.f;
#pragma unroll
        for (int rr = 0; rr < 16; ++rr) s += red[rr][threadIdx.x];
        atomicAdd(&v0[b * 64 + threadIdx.x], s);
    }
}

// ---------------------------------------------------------------------------
// Kernel 2: given v[b][n][64] (or broadcast v[b][64]),
//   s[n]   = v @ W_n            (W_n = W[:, n*16 : n*16+16], [64,16])
//   o[n]   = s / sqrt(|s|^2 + 1e-7)     (squash == L2 norm here)
//   wtil[b][n][i] = sum_d W[i, n*16+d] * o[n][d]   (unless FINAL)
// grid 32 (b), 512 threads (n = t>>4, d = t&15)
// ---------------------------------------------------------------------------
template <bool BCAST, bool FINAL>
__global__ void k_caps(const float* __restrict__ v, const float* __restrict__ W,
                       float* __restrict__ wtil, float* __restrict__ out,
                       float vscale) {
    int b = blockIdx.x;
    int t = threadIdx.x;
    __shared__ float vS[NC * 64];
    __shared__ float oS[NC][DC];
    if (BCAST) {
        if (t < 64) vS[t] = v[b * 64 + t] * vscale;
    } else {
#pragma unroll
        for (int k = 0; k < 4; ++k)
            vS[t + 512 * k] = v[b * (NC * 64) + t + 512 * k] * vscale;
    }
    __syncthreads();
    int n = t >> 4, d = t & 15;
    const float* vp = BCAST ? vS : (vS + n * 64);
    float s = 0.f;
#pragma unroll
    for (int i = 0; i < 64; ++i)
        s = fmaf(vp[i], W[i * (NC * DC) + n * DC + d], s);
    // |s|^2 over the 16 dims (lanes t&15 within the wave)
    float s2 = s * s;
#pragma unroll
    for (int off = 8; off >= 1; off >>= 1) s2 += __shfl_xor(s2, off, 16);
    float o = s / sqrtf(s2 + 1e-7f);
    if (FINAL) {
        out[b * (NC * DC) + n * DC + d] = o;
    } else {
        oS[n][d] = o;
        __syncthreads();
        // wtil[b][n][i], thread handles i = 4d..4d+3
        float4 wv;
        float* wvp = (float*)&wv;
#pragma unroll
        for (int k = 0; k < 4; ++k) {
            int i = 4 * d + k;
            float acc = 0.f;
#pragma unroll
            for (int dd = 0; dd < 16; ++dd)
                acc = fmaf(W[i * (NC * DC) + n * DC + dd], oS[n][dd], acc);
            wvp[k] = acc;
        }
        ((float4*)wtil)[(b * (NC * 64) + n * 64 + 4 * d) >> 2] = wv;
    }
}

// ---------------------------------------------------------------------------
// Kernel 3: fused routing pass. For each l:
//   logits[n] = u[l] . wtil[b][n]   -> softmax over n -> c[n]
//   vout[b][n][:] += c[n] * u[l][:]
// grid 256 (b = bid>>3, 256-l chunk), 256 threads.
// Per oct of 8 l's: step3 maps threads (g = t>>5 -> l, n = t&31),
// step5 maps threads (n = t>>3, 8 consecutive d's) doing a rank-8 update
// into registers; one atomicAdd batch at the end.
// ---------------------------------------------------------------------------
__global__ void k_route(const float* __restrict__ u, const float* __restrict__ wtil,
                        float* __restrict__ vout) {
    int b  = blockIdx.x >> 3;
    int l0 = (blockIdx.x & 7) * 256;
    int t  = threadIdx.x;
    __shared__ float wS[NC * 65];   // +1 pad: conflict-free wS[n][d] across n
    __shared__ float uS[8 * 64];
    __shared__ float cS[8 * 32];
#pragma unroll
    for (int k = 0; k < 8; ++k) {
        int idx = t + 256 * k;          // 0..2047
        int n = idx >> 6, i = idx & 63;
        wS[n * 65 + i] = wtil[b * (NC * 64) + idx];
    }
    float vacc[8] = {0.f, 0.f, 0.f, 0.f, 0.f, 0.f, 0.f, 0.f};
    const int g3 = t >> 5, n3 = t & 31;        // step3 mapping
    const int n5 = t >> 3, db = (t & 7) * 8;   // step5 mapping
    const float4* u4 = (const float4*)(u + (b * LSEQ + l0) * 64);
    for (int oct = 0; oct < 32; ++oct) {
        __syncthreads();  // protect uS/cS from previous iteration's readers
        if (t < 128) ((float4*)uS)[t] = u4[oct * 128 + t];
        __syncthreads();
        // --- logits ---
        float bb = 0.f;
        const float* up = uS + g3 * 64;
        const float* wp = wS + n3 * 65;
#pragma unroll
        for (int d = 0; d < 64; ++d) bb = fmaf(up[d], wp[d], bb);
        // --- softmax over 32 capsules (32-lane segment) ---
        float m = bb;
#pragma unroll
        for (int off = 16; off >= 1; off >>= 1)
            m = fmaxf(m, __shfl_xor(m, off, 32));
        float e = __expf(bb - m);
        float ssum = e;
#pragma unroll
        for (int off = 16; off >= 1; off >>= 1)
            ssum += __shfl_xor(ssum, off, 32);
        cS[g3 * 32 + n3] = e / ssum;
        __syncthreads();
        // --- rank-8 update into registers ---
#pragma unroll
        for (int g = 0; g < 8; ++g) {
            float c = cS[g * 32 + n5];
            const float4* ug = (const float4*)(uS + g * 64 + db);
            float4 a0 = ug[0], a1 = ug[1];
            vacc[0] = fmaf(c, a0.x, vacc[0]);
            vacc[1] = fmaf(c, a0.y, vacc[1]);
            vacc[2] = fmaf(c, a0.z, vacc[2]);
            vacc[3] = fmaf(c, a0.w, vacc[3]);
            vacc[4] = fmaf(c, a1.x, vacc[4]);
            vacc[5] = fmaf(c, a1.y, vacc[5]);
            vacc[6] = fmaf(c, a1.z, vacc[6]);
            vacc[7] = fmaf(c, a1.w, vacc[7]);
        }
    }
#pragma unroll
    for (int k = 0; k < 8; ++k)
        atomicAdd(&vout[b * (NC * 64) + n5 * 64 + db + k], vacc[k]);
}

extern "C" void kernel_launch(void* const* d_in, const int* in_sizes, int n_in,
                              void* d_out, int out_size, void* d_ws, size_t ws_size,
                              hipStream_t stream) {
    const float* u = (const float*)d_in[0];  // [32, 2048, 64] f32
    const float* W = (const float*)d_in[1];  // [1, 64, 512]  f32
    float* out = (float*)d_out;              // [32, 32, 16]  f32
    float* ws = (float*)d_ws;
    float* v0 = ws;               // 2048 floats
    float* vA = ws + 2048;        // 65536 floats
    float* vB = vA + 65536;       // 65536 floats
    float* wt = vB + 65536;       // 65536 floats

    hipMemsetAsync(v0, 0, 2048 * sizeof(float), stream);
    hipMemsetAsync(vA, 0, 65536 * sizeof(float), stream);
    hipMemsetAsync(vB, 0, 65536 * sizeof(float), stream);

    // iter 0: c uniform = 1/32 -> v is n-independent column sum
    k_sum_u<<<256, 256, 0, stream>>>(u, v0);
    k_caps<true, false><<<32, 512, 0, stream>>>(v0, W, wt, nullptr, 1.0f / 32.0f);
    // iter 1: fused logits/softmax/weighted-sum
    k_route<<<256, 256, 0, stream>>>(u, wt, vA);
    k_caps<false, false><<<32, 512, 0, stream>>>(vA, W, wt, nullptr, 1.0f);
    // iter 2
    k_route<<<256, 256, 0, stream>>>(u, wt, vB);
    k_caps<false, true><<<32, 512, 0, stream>>>(vB, W, nullptr, out, 1.0f);
}

// Round 2
// 108.327 us; speedup vs baseline: 1.9003x; 1.9003x over previous
//
#include <hip/hip_runtime.h>

#define NC 32
#define DC 16
#define LSEQ 2048

// ---------------------------------------------------------------------------
// k_sum_u: per-block partial column sums of u over 256 l's.
// grid 256 (b = bid>>3, chunk = bid&7), 256 threads. Writes v0p[bid][64].
// ---------------------------------------------------------------------------
__global__ __launch_bounds__(256) void k_sum_u(const float* __restrict__ u,
                                               float* __restrict__ v0p) {
    int b  = blockIdx.x >> 3;
    int l0 = (blockIdx.x & 7) * 256;
    int q  = threadIdx.x & 15;   // float4 column
    int r  = threadIdx.x >> 4;   // row offset 0..15
    const float4* u4 = (const float4*)u;
    float4 acc = {0.f, 0.f, 0.f, 0.f};
#pragma unroll
    for (int j = 0; j < 16; ++j) {
        int l = l0 + r + 16 * j;
        float4 x = u4[(b * LSEQ + l) * 16 + q];
        acc.x += x.x; acc.y += x.y; acc.z += x.z; acc.w += x.w;
    }
    __shared__ float red[16][64];
    red[r][q * 4 + 0] = acc.x;
    red[r][q * 4 + 1] = acc.y;
    red[r][q * 4 + 2] = acc.z;
    red[r][q * 4 + 3] = acc.w;
    __syncthreads();
    if (threadIdx.x < 64) {
        float s = 0.f;
#pragma unroll
        for (int rr = 0; rr < 16; ++rr) s += red[rr][threadIdx.x];
        v0p[blockIdx.x * 64 + threadIdx.x] = s;   // partial, no atomics
    }
}

// ---------------------------------------------------------------------------
// k_caps: fold partials -> v[b][n][64]; s = v@W_n; o = L2-normalize(s);
// wtil[b][n][i] = (W_n @ o_n)[i]  (unless FINAL: write o to out).
// grid 256 (b = bid>>3, ng = bid&7 -> capsules ng*4..ng*4+3), 64 threads.
// ---------------------------------------------------------------------------
template <bool BCAST, bool FINAL>
__global__ __launch_bounds__(64) void k_caps(const float* __restrict__ v,
                                             const float* __restrict__ W,
                                             float* __restrict__ wtil,
                                             float* __restrict__ out,
                                             float vscale) {
    int b  = blockIdx.x >> 3;
    int ng = blockIdx.x & 7;
    int t  = threadIdx.x;
    __shared__ float vS[4][72];   // 72-float row stride: float4-aligned, pad
    __shared__ float oS[4][16];
    if (BCAST) {
        // fold 8 partial sums of k_sum_u
        float s = 0.f;
#pragma unroll
        for (int ch = 0; ch < 8; ++ch) s += v[(b * 8 + ch) * 64 + t];
        s *= vscale;
#pragma unroll
        for (int n4 = 0; n4 < 4; ++n4) vS[n4][t] = s;   // replicate
    } else {
        // fold 16 route partials: v layout [b][ch][n*64+d], need rows ng*4..+3
        int row = t >> 4, col4 = t & 15;
        const float4* v4 = (const float4*)v;
        float4 a = {0.f, 0.f, 0.f, 0.f};
#pragma unroll
        for (int ch = 0; ch < 16; ++ch) {
            float4 x = v4[(b * 16 + ch) * 512 + (ng * 4 + row) * 16 + col4];
            a.x += x.x; a.y += x.y; a.z += x.z; a.w += x.w;
        }
        ((float4*)&vS[row][0])[col4] = a;
    }
    __syncthreads();
    int n4 = t >> 4, d = t & 15;
    int n  = ng * 4 + n4;
    const float* vrow = &vS[n4][0];
    float s = 0.f;
#pragma unroll
    for (int i = 0; i < 64; ++i)
        s = fmaf(vrow[i], W[i * (NC * DC) + n * DC + d], s);
    float s2 = s * s;
#pragma unroll
    for (int off = 8; off >= 1; off >>= 1) s2 += __shfl_xor(s2, off, 16);
    float o = s / sqrtf(s2 + 1e-7f);
    if (FINAL) {
        out[b * (NC * DC) + n * DC + d] = o;
    } else {
        oS[n4][d] = o;
        __syncthreads();
        // wtil[b][n][i]: thread (n4, i4 = t&15) computes i = i4*4..i4*4+3
        int i4 = t & 15;
        float4 wv;
        float* wvp = (float*)&wv;
#pragma unroll
        for (int k = 0; k < 4; ++k) {
            int i = i4 * 4 + k;
            float acc = 0.f;
#pragma unroll
            for (int dd = 0; dd < 16; ++dd)
                acc = fmaf(W[i * (NC * DC) + n * DC + dd], oS[n4][dd], acc);
            wvp[k] = acc;
        }
        ((float4*)wtil)[(b * (NC * 64) + n * 64 + i4 * 4) >> 2] = wv;
    }
}

// ---------------------------------------------------------------------------
// k_route v2: register-tiled. grid 512 (b = bid>>4, ch = bid&15 -> 128 l's),
// 128 threads = 2 waves; wave w owns l-rows [w*64, w*64+64).
// Phase A: wave computes 64lx32n logits (per-lane 8lx4n tile), softmax over n
//          in-register (shfl_xor over lc), c -> cS.
// Phase B: per-lane 4nx8d V-tile, rank-64 update from cS + uS.
// Output: per-block partial V[32][64] -> vpart[bid][2048] (no atomics).
// ---------------------------------------------------------------------------
__global__ __launch_bounds__(128) void k_route(const float* __restrict__ u,
                                               const float* __restrict__ wtil,
                                               float* __restrict__ vpart) {
    int b    = blockIdx.x >> 4;
    int ch   = blockIdx.x & 15;
    int l0   = ch * 128;
    int t    = threadIdx.x;
    int w    = t >> 6;
    int lane = t & 63;
    int lr   = lane & 7;   // phase A: l = w*64 + lr + 8*i
    int lc   = lane >> 3;  // phase A: n = lc*4 + j
    int dr   = lane & 7;   // phase B: d = dr*8 .. dr*8+7
    int nc   = lane >> 3;  // phase B: n = nc*4 + j

    __shared__ float uS[128 * 68];        // row stride 68 floats (17 float4)
    __shared__ float wS[32 * 68];
    __shared__ float cS[2 * 2304];        // per wave: c[64][36]; reused as red[2048]
    float4* uS4 = (float4*)uS;
    float4* wS4 = (float4*)wS;
    float*  cw  = cS + w * 2304;
    float4* cw4 = (float4*)cw;

    // ---- stage u-tile [128][64] and w-tile [32][64] (coalesced) ----
    const float4* ug = (const float4*)(u + (b * LSEQ + l0) * 64);
#pragma unroll
    for (int r = 0; r < 16; ++r) {
        int idx = t + 128 * r;                 // 0..2047 = row*16 + col4
        uS4[(idx >> 4) * 17 + (idx & 15)] = ug[idx];
    }
    const float4* wg = (const float4*)(wtil + b * (NC * 64));
#pragma unroll
    for (int r = 0; r < 4; ++r) {
        int idx = t + 128 * r;                 // 0..511
        wS4[(idx >> 4) * 17 + (idx & 15)] = wg[idx];
    }
    __syncthreads();

    // ---- phase A: logits (per-lane 8l x 4n register tile) ----
    float acc[8][4];
#pragma unroll
    for (int i = 0; i < 8; ++i)
#pragma unroll
        for (int j = 0; j < 4; ++j) acc[i][j] = 0.f;
    int arow = w * 64 + lr;
#pragma unroll 4
    for (int k4 = 0; k4 < 16; ++k4) {
        float4 wf[4];
#pragma unroll
        for (int j = 0; j < 4; ++j) wf[j] = wS4[(lc * 4 + j) * 17 + k4];
#pragma unroll
        for (int i = 0; i < 8; ++i) {
            float4 a = uS4[(arow + 8 * i) * 17 + k4];
#pragma unroll
            for (int j = 0; j < 4; ++j) {
                acc[i][j] = fmaf(a.x, wf[j].x, acc[i][j]);
                acc[i][j] = fmaf(a.y, wf[j].y, acc[i][j]);
                acc[i][j] = fmaf(a.z, wf[j].z, acc[i][j]);
                acc[i][j] = fmaf(a.w, wf[j].w, acc[i][j]);
            }
        }
    }

    // ---- softmax over n (4 regs x 8 lc-groups) per l-row i ----
#pragma unroll
    for (int i = 0; i < 8; ++i) {
        float m = fmaxf(fmaxf(acc[i][0], acc[i][1]), fmaxf(acc[i][2], acc[i][3]));
        m = fmaxf(m, __shfl_xor(m, 8));
        m = fmaxf(m, __shfl_xor(m, 16));
        m = fmaxf(m, __shfl_xor(m, 32));
        float e0 = __expf(acc[i][0] - m), e1 = __expf(acc[i][1] - m);
        float e2 = __expf(acc[i][2] - m), e3 = __expf(acc[i][3] - m);
        float ss = e0 + e1 + e2 + e3;
        ss += __shfl_xor(ss, 8);
        ss += __shfl_xor(ss, 16);
        ss += __shfl_xor(ss, 32);
        float inv = 1.f / ss;
        float4 cvv = {e0 * inv, e1 * inv, e2 * inv, e3 * inv};
        cw4[(lr + 8 * i) * 9 + lc] = cvv;     // c[lrel][lc*4..+3], stride 36 floats
    }
    __syncthreads();   // (paranoia: cS visibility; also aligns waves)

    // ---- phase B: V[n=nc*4+j][d=dr*8..+7] += sum_l c[l][n]*u[l][d] ----
    float vacc[4][8];
#pragma unroll
    for (int j = 0; j < 4; ++j)
#pragma unroll
        for (int k = 0; k < 8; ++k) vacc[j][k] = 0.f;
#pragma unroll 8
    for (int lrel = 0; lrel < 64; ++lrel) {
        float4 cv = cw4[lrel * 9 + nc];
        const float4* ur = uS4 + (w * 64 + lrel) * 17 + dr * 2;
        float4 u0 = ur[0], u1 = ur[1];
        float* cp = (float*)&cv;
#pragma unroll
        for (int j = 0; j < 4; ++j) {
            float c = cp[j];
            vacc[j][0] = fmaf(c, u0.x, vacc[j][0]);
            vacc[j][1] = fmaf(c, u0.y, vacc[j][1]);
            vacc[j][2] = fmaf(c, u0.z, vacc[j][2]);
            vacc[j][3] = fmaf(c, u0.w, vacc[j][3]);
            vacc[j][4] = fmaf(c, u1.x, vacc[j][4]);
            vacc[j][5] = fmaf(c, u1.y, vacc[j][5]);
            vacc[j][6] = fmaf(c, u1.z, vacc[j][6]);
            vacc[j][7] = fmaf(c, u1.w, vacc[j][7]);
        }
    }

    // ---- cross-wave reduce: red[w][n*64+d] in cS (own-wave region, safe) ----
#pragma unroll
    for (int j = 0; j < 4; ++j) {
        float* rp = cw + (nc * 4 + j) * 64 + dr * 8;
        float4 r0 = {vacc[j][0], vacc[j][1], vacc[j][2], vacc[j][3]};
        float4 r1 = {vacc[j][4], vacc[j][5], vacc[j][6], vacc[j][7]};
        ((float4*)rp)[0] = r0;
        ((float4*)rp)[1] = r1;
    }
    __syncthreads();
    // fold the 2 waves and store the block partial (coalesced)
    float4* cS4 = (float4*)cS;
    float4* vp4 = (float4*)(vpart + blockIdx.x * 2048);
#pragma unroll
    for (int s = 0; s < 4; ++s) {
        int idx4 = t + 128 * s;               // 0..511
        float4 a = cS4[idx4];
        float4 c2 = cS4[576 + idx4];          // 2304 floats / 4
        float4 o = {a.x + c2.x, a.y + c2.y, a.z + c2.z, a.w + c2.w};
        vp4[idx4] = o;
    }
}

extern "C" void kernel_launch(void* const* d_in, const int* in_sizes, int n_in,
                              void* d_out, int out_size, void* d_ws, size_t ws_size,
                              hipStream_t stream) {
    const float* u = (const float*)d_in[0];  // [32, 2048, 64] f32
    const float* W = (const float*)d_in[1];  // [1, 64, 512]  f32
    float* out = (float*)d_out;              // [32, 32, 16]  f32
    float* ws  = (float*)d_ws;
    float* v0p   = ws;                 // 256*64      = 16384 floats
    float* wt    = ws + 16384;         // 32*32*64    = 65536 floats
    float* vpart = ws + 16384 + 65536; // 512*2048    = 1048576 floats (~4 MB)

    // iter 0: uniform c = 1/32 -> column sum
    k_sum_u<<<256, 256, 0, stream>>>(u, v0p);
    k_caps<true, false><<<256, 64, 0, stream>>>(v0p, W, wt, nullptr, 1.0f / 32.0f);
    // iter 1
    k_route<<<512, 128, 0, stream>>>(u, wt, vpart);
    k_caps<false, false><<<256, 64, 0, stream>>>(vpart, W, wt, nullptr, 1.0f);
    // iter 2
    k_route<<<512, 128, 0, stream>>>(u, wt, vpart);
    k_caps<false, true><<<256, 64, 0, stream>>>(vpart, W, nullptr, out, 1.0f);
}